// Round 4
// baseline (683.106 us; speedup 1.0000x reference)
//
#include <hip/hip_runtime.h>
#include <stdint.h>

// Problem constants (from setup_inputs: B=2, Nr=40962, in_ch=128, out_ch=64)
// ALL float tensors are FP32 on device (reference uses jnp.float32 throughout).
#define NR     40962
#define NH     163842      // 4*NR-6
#define NR7    286734      // NR*7
#define M_UP   40962       // per-batch rows for up-GEMM
#define N_UP   448
#define K_UP   128
#define M_CV   327684      // B*NH
#define K_C1   896
#define K_C2   448
#define BN_EPS 1e-5f
#define SLOPE  0.2f

typedef __attribute__((ext_vector_type(8))) short  short8;
typedef __attribute__((ext_vector_type(4))) float  f32x4;
typedef unsigned short ushort_t;

__device__ __forceinline__ ushort_t f2bf(float f) {
  union { float f; uint32_t u; } v; v.f = f;
  uint32_t r = v.u + 0x7fffu + ((v.u >> 16) & 1u);  // round-to-nearest-even
  return (ushort_t)(r >> 16);
}
__device__ __forceinline__ float bf2f(ushort_t h) {
  union { uint32_t u; float f; } v; v.u = ((uint32_t)h) << 16;
  return v.f;
}
__device__ __forceinline__ int clampi(int v, int hi) {  // [0, hi)
  v = v < 0 ? 0 : v;
  return v >= hi ? hi - 1 : v;
}

// ---------------------------------------------------------------------------
// MFMA GEMM, bf16 compute / fp32 accumulate.
// MODE 0: A = x1 fp32 (direct rows), out = h bf16.
// MODE 1: conv1 gather, K=896: k->(j=k/128,c=k%128), idx=neigh[n*7+j];
//         c<64 -> xup bf16, c>=64 -> x2 fp32 (cvt). out = y1 bf16.
// MODE 2: conv2 gather, K=448: k->(j=k/64,c=k%64); A = y1 bf16. out = FP32.
// Tile 64x64, 256 thr = 4 waves, wave w owns rows [16w,16w+16).
// LDS rows padded to 40 bf16 (80 B).
// ---------------------------------------------------------------------------
template<int MODE>
__global__ __launch_bounds__(256) void gemm_mfma(
    const float*    __restrict__ Af,     // MODE0: x1
    const ushort_t* __restrict__ Ab,     // MODE1: xup bf16; MODE2: y1 bf16
    const float*    __restrict__ Af2,    // MODE1: x2 fp32
    const int*      __restrict__ neigh,
    const float*    __restrict__ W,      // fp32 weights
    const float*    __restrict__ bias,   // fp32 bias
    void*           __restrict__ OutV,
    int M, int N, int K)
{
  __shared__ __align__(16) ushort_t As[64 * 40];
  __shared__ __align__(16) ushort_t Bs[64 * 40];

  const int tid   = threadIdx.x;
  const int mTile = blockIdx.y * 64;
  const int nTile = blockIdx.x * 64;

  const int wv   = tid >> 6;
  const int lane = tid & 63;
  const int r16  = lane & 15;
  const int q    = lane >> 4;

  f32x4 acc[4];
#pragma unroll
  for (int i = 0; i < 4; ++i) acc[i] = (f32x4){0.f, 0.f, 0.f, 0.f};

  // A staging map: thread -> (tile row, 8-elem k segment)
  const int ar  = tid >> 2;          // 0..63 tile row
  const int aks = (tid & 3) * 8;     // k offset within 32-chunk
  int a_m = mTile + ar; if (a_m >= M) a_m = M - 1;   // clamp tail (store-masked)
  // B staging: lanes -> consecutive cols, 8 k's per thread
  const int bcol = tid & 63;
  const int bks  = (tid >> 6) * 8;

  int gb = 0, gn = 0;
  if constexpr (MODE != 0) { gb = a_m / NH; gn = a_m - gb * NH; }

  const int nChunks = K / 32;
  for (int ch = 0; ch < nChunks; ++ch) {
    const int k0 = ch * 32;
    __syncthreads();
    { // ---- stage A chunk (64 x 32) as bf16 ----
      const int kk = k0 + aks;
      short8 av;
      if constexpr (MODE == 0) {
        const float4 f0 = *(const float4*)(Af + (size_t)a_m * K + kk);
        const float4 f1 = *(const float4*)(Af + (size_t)a_m * K + kk + 4);
        av[0]=(short)f2bf(f0.x); av[1]=(short)f2bf(f0.y);
        av[2]=(short)f2bf(f0.z); av[3]=(short)f2bf(f0.w);
        av[4]=(short)f2bf(f1.x); av[5]=(short)f2bf(f1.y);
        av[6]=(short)f2bf(f1.z); av[7]=(short)f2bf(f1.w);
      } else if constexpr (MODE == 1) {
        const int j = kk >> 7;
        const int c = kk & 127;
        const int idx = clampi(neigh[gn * 7 + j], NH);
        const size_t rbase = (size_t)(gb * NH + idx) * 64;
        if (c < 64) {
          av = *(const short8*)(Ab + rbase + c);
        } else {
          const float4 f0 = *(const float4*)(Af2 + rbase + (c - 64));
          const float4 f1 = *(const float4*)(Af2 + rbase + (c - 64) + 4);
          av[0]=(short)f2bf(f0.x); av[1]=(short)f2bf(f0.y);
          av[2]=(short)f2bf(f0.z); av[3]=(short)f2bf(f0.w);
          av[4]=(short)f2bf(f1.x); av[5]=(short)f2bf(f1.y);
          av[6]=(short)f2bf(f1.z); av[7]=(short)f2bf(f1.w);
        }
      } else {
        const int j = kk >> 6;
        const int c = kk & 63;
        const int idx = clampi(neigh[gn * 7 + j], NH);
        av = *(const short8*)(Ab + (size_t)(gb * NH + idx) * 64 + c);
      }
      *(short8*)&As[ar * 40 + aks] = av;
    }
    { // ---- stage B chunk transposed: Bs[col][k], fp32 -> bf16 ----
      short8 bv;
#pragma unroll
      for (int i = 0; i < 8; ++i)
        bv[i] = (short)f2bf(W[(size_t)(k0 + bks + i) * N + (nTile + bcol)]);
      *(short8*)&Bs[bcol * 40 + bks] = bv;
    }
    __syncthreads();
    // A frag A[m=lane&15][k=q*8+j]; B frag B[k=q*8+j][n=lane&15]
    short8 a = *(const short8*)&As[(wv * 16 + r16) * 40 + q * 8];
#pragma unroll
    for (int ct = 0; ct < 4; ++ct) {
      short8 b = *(const short8*)&Bs[(ct * 16 + r16) * 40 + q * 8];
      acc[ct] = __builtin_amdgcn_mfma_f32_16x16x32_bf16(a, b, acc[ct], 0, 0, 0);
    }
  }

  // epilogue: C/D layout col=lane&15, row=(lane>>4)*4+reg
#pragma unroll
  for (int ct = 0; ct < 4; ++ct) {
    const int colg = nTile + ct * 16 + r16;
    const float bv = bias[colg];
#pragma unroll
    for (int i = 0; i < 4; ++i) {
      const int rowg = mTile + wv * 16 + q * 4 + i;
      if (rowg < M) {
        if constexpr (MODE == 2)
          ((float*)OutV)[(size_t)rowg * N + colg] = acc[ct][i] + bv;
        else
          ((ushort_t*)OutV)[(size_t)rowg * N + colg] = f2bf(acc[ct][i] + bv);
      }
    }
  }
}

// ---------------------------------------------------------------------------
// Per batch: xup[n][0:64] = upconv pick/mean from h_b ((NR,448) viewed as
// (NR7,64)), bf16 in/out. One thread per 8-channel segment.
// ---------------------------------------------------------------------------
__global__ __launch_bounds__(256) void build_xup_kernel(
    const ushort_t* __restrict__ h,     // (NR7, 64) bf16, this batch
    const int*      __restrict__ top,   // (NR)
    const int*      __restrict__ down,  // (NH-NR, 2)
    ushort_t*       __restrict__ xup,   // (NH, 64) bf16, this batch
    long long total)                    // NH*8
{
  const long long gid = (long long)blockIdx.x * 256 + threadIdx.x;
  if (gid >= total) return;
  const int n  = (int)(gid >> 3);
  const int c0 = (int)(gid & 7) * 8;
  short8 v;
  if (n < NR) {
    const int idx = clampi(top[n], NR7);
    v = *(const short8*)(h + (size_t)idx * 64 + c0);
  } else {
    const int d  = n - NR;
    const int i0 = clampi(down[d * 2], NR7);
    const int i1 = clampi(down[d * 2 + 1], NR7);
    short8 u0 = *(const short8*)(h + (size_t)i0 * 64 + c0);
    short8 u1 = *(const short8*)(h + (size_t)i1 * 64 + c0);
#pragma unroll
    for (int i = 0; i < 8; ++i)
      v[i] = (short)f2bf(0.5f * (bf2f((ushort_t)u0[i]) + bf2f((ushort_t)u1[i])));
  }
  *(short8*)(xup + (size_t)n * 64 + c0) = v;
}

// ---------------------------------------------------------------------------
// Per-channel sum & sumsq over (rows x 64ch) buffer -> stats[0:64],[64:128]
// ---------------------------------------------------------------------------
template<bool F32>
__global__ __launch_bounds__(256) void stats_kernel(
    const void* __restrict__ bufV, float* __restrict__ stats, int rows)
{
  const int tid = threadIdx.x;
  const int c   = tid & 63;
  const int rl  = tid >> 6;
  float s = 0.f, s2 = 0.f;
  for (int r = blockIdx.x * 4 + rl; r < rows; r += gridDim.x * 4) {
    float v;
    if constexpr (F32) v = ((const float*)bufV)[(size_t)r * 64 + c];
    else               v = bf2f(((const ushort_t*)bufV)[(size_t)r * 64 + c]);
    s += v; s2 += v * v;
  }
  __shared__ float sh[2][256];
  sh[0][tid] = s; sh[1][tid] = s2;
  __syncthreads();
  if (tid < 64) {
#pragma unroll
    for (int i = 1; i < 4; ++i) { s += sh[0][tid + 64 * i]; s2 += sh[1][tid + 64 * i]; }
    atomicAdd(&stats[c], s);
    atomicAdd(&stats[64 + c], s2);
  }
}

__global__ void zero_stats_kernel(float* __restrict__ stats) {
  stats[threadIdx.x] = 0.f;   // launch with 256 threads
}

__global__ void finalize_kernel(float* __restrict__ stats,
                                const float* __restrict__ gamma,
                                const float* __restrict__ beta)
{
  const int c = threadIdx.x;  // 64 threads
  const float invN = 1.0f / (float)M_CV;
  const float mean = stats[c] * invN;
  float var = stats[64 + c] * invN - mean * mean;   // population var (ddof=0)
  var = fmaxf(var, 0.f);
  const float sc = gamma[c] * rsqrtf(var + BN_EPS);
  stats[128 + c] = sc;
  stats[192 + c] = beta[c] - mean * sc;
}

// In-place y = lrelu(v*scale[c] + shift[c]).
// F32: 4 floats/thread; bf16: 8 elems/thread.
template<bool F32>
__global__ __launch_bounds__(256) void bnl_kernel(
    void* __restrict__ bufV, const float* __restrict__ stats, long long nvec)
{
  const long long gid = (long long)blockIdx.x * 256 + threadIdx.x;
  if (gid >= nvec) return;
  if constexpr (F32) {
    float* buf = (float*)bufV;
    const int c0 = (int)((gid * 4) & 63);
    f32x4 v = *(f32x4*)(buf + gid * 4);
#pragma unroll
    for (int i = 0; i < 4; ++i) {
      float y = v[i] * stats[128 + c0 + i] + stats[192 + c0 + i];
      v[i] = (y >= 0.f) ? y : SLOPE * y;
    }
    *(f32x4*)(buf + gid * 4) = v;
  } else {
    ushort_t* buf = (ushort_t*)bufV;
    const int c0 = (int)((gid * 8) & 63);
    short8 v = *(short8*)(buf + gid * 8);
#pragma unroll
    for (int i = 0; i < 8; ++i) {
      float y = bf2f((ushort_t)v[i]) * stats[128 + c0 + i] + stats[192 + c0 + i];
      y = (y >= 0.f) ? y : SLOPE * y;
      v[i] = (short)f2bf(y);
    }
    *(short8*)(buf + gid * 8) = v;
  }
}

// ---------------------------------------------------------------------------
extern "C" void kernel_launch(void* const* d_in, const int* in_sizes, int n_in,
                              void* d_out, int out_size, void* d_ws, size_t ws_size,
                              hipStream_t stream)
{
  const float* x1   = (const float*)d_in[0];
  const float* x2   = (const float*)d_in[1];
  const int*   neigh= (const int*)d_in[2];
  const int*   top  = (const int*)d_in[3];
  const int*   down = (const int*)d_in[4];
  const float* upW  = (const float*)d_in[5];
  const float* upb  = (const float*)d_in[6];
  const float* c1W  = (const float*)d_in[7];
  const float* c1b  = (const float*)d_in[8];
  const float* g1   = (const float*)d_in[9];
  const float* b1   = (const float*)d_in[10];
  const float* c2W  = (const float*)d_in[11];
  const float* c2b  = (const float*)d_in[12];
  const float* g2   = (const float*)d_in[13];
  const float* b2   = (const float*)d_in[14];

  // Memory plan (fp32 I/O, bf16 intermediates):
  //   ws[0, 41943552): per-batch h bf16 (36.7MB), then y1 bf16 (41.94MB).
  //   d_out (83.9MB fp32): first 41.94MB = xup bf16 during phases 1-2;
  //     st1 (1KB fp32) overlays it after conv1; conv2 overwrites all of
  //     d_out with fp32 output; st2 overlays ws (y1 dead) for BN2.
  ushort_t* hbuf = (ushort_t*)d_ws;
  ushort_t* ybuf = (ushort_t*)d_ws;
  ushort_t* xupb = (ushort_t*)d_out;
  float*    outb = (float*)d_out;
  float*    st1  = (float*)d_out;   // live only between conv1 and conv2
  float*    st2  = (float*)d_ws;    // live only after conv2

  // Phase 1 — per batch: h_b = x1_b @ up_W + up_b (bf16 out); xup_b = upconv
  for (int b = 0; b < 2; ++b) {
    gemm_mfma<0><<<dim3(N_UP / 64, (M_UP + 63) / 64), 256, 0, stream>>>(
        x1 + (size_t)b * M_UP * K_UP, nullptr, nullptr, nullptr, upW, upb,
        hbuf, M_UP, N_UP, K_UP);
    build_xup_kernel<<<(int)(((long long)NH * 8 + 255) / 256), 256, 0, stream>>>(
        hbuf, top, down, xupb + (size_t)b * NH * 64, (long long)NH * 8);
  }

  // Phase 2 — y1 = meshconv1([xup bf16 | x2 fp32])  -> ws (bf16)
  gemm_mfma<1><<<dim3(1, (M_CV + 63) / 64), 256, 0, stream>>>(
      nullptr, xupb, x2, neigh, c1W, c1b, ybuf, M_CV, 64, K_C1);

  // BN1 + leaky on y1 (st1 overlays dead xup region of d_out)
  zero_stats_kernel<<<1, 256, 0, stream>>>(st1);
  stats_kernel<false><<<2048, 256, 0, stream>>>(ybuf, st1, M_CV);
  finalize_kernel<<<1, 64, 0, stream>>>(st1, g1, b1);
  {
    const long long nvec = (long long)M_CV * 64 / 8;
    bnl_kernel<false><<<(int)((nvec + 255) / 256), 256, 0, stream>>>(
        ybuf, st1, nvec);
  }

  // Phase 3 — out = meshconv2(y1)  -> d_out (fp32, clobbers xup + st1)
  gemm_mfma<2><<<dim3(1, (M_CV + 63) / 64), 256, 0, stream>>>(
      nullptr, ybuf, nullptr, neigh, c2W, c2b, outb, M_CV, 64, K_C2);

  // BN2 + leaky in-place on d_out (st2 overlays dead y1 region of ws)
  zero_stats_kernel<<<1, 256, 0, stream>>>(st2);
  stats_kernel<true><<<2048, 256, 0, stream>>>(outb, st2, M_CV);
  finalize_kernel<<<1, 64, 0, stream>>>(st2, g2, b2);
  {
    const long long nvec = (long long)M_CV * 64 / 4;
    bnl_kernel<true><<<(int)((nvec + 255) / 256), 256, 0, stream>>>(
        outb, st2, nvec);
  }
}

// Round 6
// 551.090 us; speedup vs baseline: 1.2396x; 1.2396x over previous
//
#include <hip/hip_runtime.h>
#include <stdint.h>

// Problem constants (B=2, Nr=40962, in_ch=128, out_ch=64). FP32 I/O.
#define NR     40962
#define NH     163842      // 4*NR-6
#define NR7    286734      // NR*7
#define M_UP   40962       // per-batch rows for up-GEMM
#define N_UP   448
#define K_UP   128
#define M_CV   327684      // B*NH
#define K_C1   896
#define K_C2   448
#define BN_EPS 1e-5f
#define SLOPE  0.2f

typedef __attribute__((ext_vector_type(8))) short  short8;
typedef __attribute__((ext_vector_type(4))) float  f32x4;
typedef unsigned short ushort_t;

__device__ __forceinline__ ushort_t f2bf(float f) {
  union { float f; uint32_t u; } v; v.f = f;
  uint32_t r = v.u + 0x7fffu + ((v.u >> 16) & 1u);  // RNE
  return (ushort_t)(r >> 16);
}
__device__ __forceinline__ float bf2f(ushort_t h) {
  union { uint32_t u; float f; } v; v.u = ((uint32_t)h) << 16;
  return v.f;
}
__device__ __forceinline__ int clampi(int v, int hi) {
  v = v < 0 ? 0 : v;
  return v >= hi ? hi - 1 : v;
}

// ---------------------------------------------------------------------------
// MFMA GEMM, 128x64 tile, bf16 compute / fp32 accumulate.
// MODE 0: A = x1bf (direct rows). out bf16.
// MODE 1: conv1 gather K=896: k->(j=k>>7,c=k&127); c<64 -> xup bf16,
//         else x2 fp32 (cvt in-kernel). out bf16.
// MODE 2: conv2 gather K=448: k->(j=k>>6,c=k&63); A = y1 bf16. out fp32.
// PRE_B: B staged from bf16 W^T [n][K] (vector); else fp32 W [k][N] (scalar).
// FSTATS: per-channel sum/sumsq of (acc+bias) -> statsPart[64 slices][128].
// 256 thr = 4 waves; wave w owns rows [32w, 32w+32) as 2 MFMA row-frags.
// LDS rows padded to 40 ushorts (80 B).
// ---------------------------------------------------------------------------
template<int MODE, bool PRE_B, bool FSTATS>
__global__ __launch_bounds__(256) void gemm_mfma(
    const ushort_t* __restrict__ Ab,     // MODE0 x1bf / MODE1 xup / MODE2 y1
    const float*    __restrict__ Af2,    // MODE1: x2 fp32
    const int*      __restrict__ neigh,
    const ushort_t* __restrict__ Wt,     // PRE_B: bf16 [n][K]
    const float*    __restrict__ Wf,     // !PRE_B: fp32 [k][N]
    const float*    __restrict__ bias,
    void*           __restrict__ OutV,
    float*          __restrict__ statsPart,
    int M, int N, int K)
{
  __shared__ __align__(16) ushort_t As[128 * 40];
  __shared__ __align__(16) ushort_t Bs[64 * 40];

  const int tid   = threadIdx.x;
  const int mTile = blockIdx.y * 128;
  const int nTile = blockIdx.x * 64;

  const int wv   = tid >> 6;
  const int lane = tid & 63;
  const int r16  = lane & 15;
  const int q    = lane >> 4;

  f32x4 acc[2][4];
#pragma unroll
  for (int a = 0; a < 2; ++a)
#pragma unroll
    for (int i = 0; i < 4; ++i) acc[a][i] = (f32x4){0.f, 0.f, 0.f, 0.f};

  // A staging: thread -> (row ar, 16-elem k segment)
  const int ar  = tid >> 1;            // 0..127
  const int aks = (tid & 1) * 16;      // 0 or 16
  int a_m = mTile + ar; if (a_m >= M) a_m = M - 1;  // clamp tail (store-masked)
  // B staging: thread -> (col bn, 8-elem k segment)
  const int bn  = tid >> 2;            // 0..63
  const int bks = (tid & 3) * 8;

  int gb = 0, gn = 0;
  if constexpr (MODE != 0) { gb = a_m / NH; gn = a_m - gb * NH; }

  const int nChunks = K / 32;
  for (int ch = 0; ch < nChunks; ++ch) {
    const int k0 = ch * 32;
    __syncthreads();
    { // ---- stage A (128 x 32) ----
      const int kk = k0 + aks;         // multiple of 16
      short8 a0, a1;
      if constexpr (MODE == 0) {
        const ushort_t* src = Ab + (size_t)a_m * K + kk;
        a0 = *(const short8*)(src);
        a1 = *(const short8*)(src + 8);
      } else if constexpr (MODE == 1) {
        const int j = kk >> 7;
        const int c = kk & 127;
        const int idx = clampi(neigh[gn * 7 + j], NH);
        const size_t rbase = (size_t)(gb * NH + idx) * 64;
        if (c < 64) {
          const ushort_t* src = Ab + rbase + c;
          a0 = *(const short8*)(src);
          a1 = *(const short8*)(src + 8);
        } else {
          const float* fp = Af2 + rbase + (c - 64);
          const float4 f0 = *(const float4*)(fp);
          const float4 f1 = *(const float4*)(fp + 4);
          const float4 f2 = *(const float4*)(fp + 8);
          const float4 f3 = *(const float4*)(fp + 12);
          a0[0]=(short)f2bf(f0.x); a0[1]=(short)f2bf(f0.y);
          a0[2]=(short)f2bf(f0.z); a0[3]=(short)f2bf(f0.w);
          a0[4]=(short)f2bf(f1.x); a0[5]=(short)f2bf(f1.y);
          a0[6]=(short)f2bf(f1.z); a0[7]=(short)f2bf(f1.w);
          a1[0]=(short)f2bf(f2.x); a1[1]=(short)f2bf(f2.y);
          a1[2]=(short)f2bf(f2.z); a1[3]=(short)f2bf(f2.w);
          a1[4]=(short)f2bf(f3.x); a1[5]=(short)f2bf(f3.y);
          a1[6]=(short)f2bf(f3.z); a1[7]=(short)f2bf(f3.w);
        }
      } else {
        const int j = kk >> 6;
        const int c = kk & 63;
        const int idx = clampi(neigh[gn * 7 + j], NH);
        const ushort_t* src = Ab + (size_t)(gb * NH + idx) * 64 + c;
        a0 = *(const short8*)(src);
        a1 = *(const short8*)(src + 8);
      }
      *(short8*)&As[ar * 40 + aks]     = a0;
      *(short8*)&As[ar * 40 + aks + 8] = a1;
    }
    { // ---- stage B (64 cols x 32 k), transposed layout Bs[col][k] ----
      short8 bv;
      if constexpr (PRE_B) {
        bv = *(const short8*)(Wt + (size_t)(nTile + bn) * K + k0 + bks);
      } else {
#pragma unroll
        for (int i = 0; i < 8; ++i)
          bv[i] = (short)f2bf(Wf[(size_t)(k0 + bks + i) * N + (nTile + bn)]);
      }
      *(short8*)&Bs[bn * 40 + bks] = bv;
    }
    __syncthreads();
    // A frag rows wv*32 + af*16 + r16; B frag B[k=q*8+j][n=lane&15]
    short8 a0 = *(const short8*)&As[(wv * 32 + r16) * 40 + q * 8];
    short8 a1 = *(const short8*)&As[(wv * 32 + 16 + r16) * 40 + q * 8];
#pragma unroll
    for (int ct = 0; ct < 4; ++ct) {
      short8 b = *(const short8*)&Bs[(ct * 16 + r16) * 40 + q * 8];
      acc[0][ct] = __builtin_amdgcn_mfma_f32_16x16x32_bf16(a0, b, acc[0][ct], 0, 0, 0);
      acc[1][ct] = __builtin_amdgcn_mfma_f32_16x16x32_bf16(a1, b, acc[1][ct], 0, 0, 0);
    }
  }

  // epilogue: C/D layout col=lane&15, row=(lane>>4)*4+reg
  float s[4]  = {0.f, 0.f, 0.f, 0.f};
  float s2[4] = {0.f, 0.f, 0.f, 0.f};
#pragma unroll
  for (int ct = 0; ct < 4; ++ct) {
    const int colg = nTile + ct * 16 + r16;
    const float bv = bias[colg];
#pragma unroll
    for (int af = 0; af < 2; ++af) {
#pragma unroll
      for (int i = 0; i < 4; ++i) {
        const int rowg = mTile + wv * 32 + af * 16 + q * 4 + i;
        const float y = acc[af][ct][i] + bv;
        if (rowg < M) {
          if constexpr (MODE == 2)
            ((float*)OutV)[(size_t)rowg * N + colg] = y;
          else
            ((ushort_t*)OutV)[(size_t)rowg * N + colg] = f2bf(y);
          if constexpr (FSTATS) { s[ct] += y; s2[ct] += y * y; }
        }
      }
    }
  }

  if constexpr (FSTATS) {
    __syncthreads();                     // all LDS reads done; reuse As
    float* Sred  = (float*)&As[0];       // [4 waves][64 ch]
    float* S2red = Sred + 256;
#pragma unroll
    for (int ct = 0; ct < 4; ++ct) {
      float v = s[ct], w = s2[ct];
      v += __shfl_xor(v, 16, 64); v += __shfl_xor(v, 32, 64);
      w += __shfl_xor(w, 16, 64); w += __shfl_xor(w, 32, 64);
      if (q == 0) {
        Sred[wv * 64 + ct * 16 + r16]  = v;
        S2red[wv * 64 + ct * 16 + r16] = w;
      }
    }
    __syncthreads();
    if (tid < 64) {
      float v = Sred[tid] + Sred[64 + tid] + Sred[128 + tid] + Sred[192 + tid];
      float w = S2red[tid] + S2red[64 + tid] + S2red[128 + tid] + S2red[192 + tid];
      float* p = statsPart + (size_t)(blockIdx.y & 63) * 128;
      atomicAdd(&p[tid], v);
      atomicAdd(&p[64 + tid], w);
    }
  }
}

// ---------------------------------------------------------------------------
// Per batch: xup[n][0:64] = upconv pick/mean from h_b ((NR,448) as (NR7,64)).
// ---------------------------------------------------------------------------
__global__ __launch_bounds__(256) void build_xup_kernel(
    const ushort_t* __restrict__ h, const int* __restrict__ top,
    const int* __restrict__ down, ushort_t* __restrict__ xup, long long total)
{
  const long long gid = (long long)blockIdx.x * 256 + threadIdx.x;
  if (gid >= total) return;
  const int n  = (int)(gid >> 3);
  const int c0 = (int)(gid & 7) * 8;
  short8 v;
  if (n < NR) {
    const int idx = clampi(top[n], NR7);
    v = *(const short8*)(h + (size_t)idx * 64 + c0);
  } else {
    const int d  = n - NR;
    const int i0 = clampi(down[d * 2], NR7);
    const int i1 = clampi(down[d * 2 + 1], NR7);
    short8 u0 = *(const short8*)(h + (size_t)i0 * 64 + c0);
    short8 u1 = *(const short8*)(h + (size_t)i1 * 64 + c0);
#pragma unroll
    for (int i = 0; i < 8; ++i)
      v[i] = (short)f2bf(0.5f * (bf2f((ushort_t)u0[i]) + bf2f((ushort_t)u1[i])));
  }
  *(short8*)(xup + (size_t)n * 64 + c0) = v;
}

// fp32 -> bf16, 8 elems/thread
__global__ __launch_bounds__(256) void cvt_bf_kernel(
    const float* __restrict__ src, ushort_t* __restrict__ dst, long long n8)
{
  const long long gid = (long long)blockIdx.x * 256 + threadIdx.x;
  if (gid >= n8) return;
  const float4 f0 = *(const float4*)(src + gid * 8);
  const float4 f1 = *(const float4*)(src + gid * 8 + 4);
  short8 v;
  v[0]=(short)f2bf(f0.x); v[1]=(short)f2bf(f0.y);
  v[2]=(short)f2bf(f0.z); v[3]=(short)f2bf(f0.w);
  v[4]=(short)f2bf(f1.x); v[5]=(short)f2bf(f1.y);
  v[6]=(short)f2bf(f1.z); v[7]=(short)f2bf(f1.w);
  *(short8*)(dst + gid * 8) = v;
}

// Transpose+convert weights: W[k][n] fp32 -> Wt[n][k] bf16.
// gid ranges: [0,57344) upWt; [57344,114688) c1Wt; [114688,143360) c2Wt(opt)
__global__ __launch_bounds__(256) void cvt_w_kernel(
    const float* __restrict__ upW, const float* __restrict__ c1W,
    const float* __restrict__ c2W, ushort_t* __restrict__ upWt,
    ushort_t* __restrict__ c1Wt, ushort_t* __restrict__ c2Wt)
{
  const int gid = blockIdx.x * 256 + threadIdx.x;
  if (gid < 57344) {                         // 448 x 128
    const int n = gid >> 7, k = gid & 127;
    upWt[gid] = f2bf(upW[k * 448 + n]);
  } else if (gid < 114688) {                 // 64 x 896
    const int o = gid - 57344;
    const int n = o / 896, k = o - n * 896;
    c1Wt[o] = f2bf(c1W[k * 64 + n]);
  } else if (gid < 143360) {                 // 64 x 448
    if (c2Wt) {
      const int o = gid - 114688;
      const int n = o / 448, k = o - n * 448;
      c2Wt[o] = f2bf(c2W[k * 64 + n]);
    }
  }
}

__global__ __launch_bounds__(256) void zero_kernel(float* __restrict__ p, int n) {
  const int gid = blockIdx.x * 256 + threadIdx.x;
  if (gid < n) p[gid] = 0.f;
}

// Fallback separate stats over fp32 buffer -> partial slices
__global__ __launch_bounds__(256) void stats_f32_kernel(
    const float* __restrict__ buf, float* __restrict__ part, int rows)
{
  const int tid = threadIdx.x;
  const int c   = tid & 63;
  const int rl  = tid >> 6;
  float s = 0.f, s2 = 0.f;
  for (int r = blockIdx.x * 4 + rl; r < rows; r += gridDim.x * 4) {
    const float v = buf[(size_t)r * 64 + c];
    s += v; s2 += v * v;
  }
  __shared__ float sh[2][256];
  sh[0][tid] = s; sh[1][tid] = s2;
  __syncthreads();
  if (tid < 64) {
#pragma unroll
    for (int i = 1; i < 4; ++i) { s += sh[0][tid + 64 * i]; s2 += sh[1][tid + 64 * i]; }
    float* p = part + (size_t)(blockIdx.x & 63) * 128;
    atomicAdd(&p[c], s);
    atomicAdd(&p[64 + c], s2);
  }
}

// Reduce 64 partial slices -> final [sc[64] | sh[64]] at part+8192
__global__ void finalize_kernel(float* __restrict__ part,
                                const float* __restrict__ gamma,
                                const float* __restrict__ beta)
{
  const int c = threadIdx.x;  // 64
  float s = 0.f, s2 = 0.f;
  for (int i = 0; i < 64; ++i) { s += part[i * 128 + c]; s2 += part[i * 128 + 64 + c]; }
  const float invN = 1.0f / (float)M_CV;
  const float mean = s * invN;
  float var = fmaxf(s2 * invN - mean * mean, 0.f);
  const float sc = gamma[c] * rsqrtf(var + BN_EPS);
  float* fin = part + 8192;
  fin[c] = sc;
  fin[64 + c] = beta[c] - mean * sc;
}

// In-place y = lrelu(v*sc[c] + sh[c]); fin = [sc[64] | sh[64]]
template<bool F32>
__global__ __launch_bounds__(256) void bnl_kernel(
    void* __restrict__ bufV, const float* __restrict__ fin, long long nvec)
{
  const long long gid = (long long)blockIdx.x * 256 + threadIdx.x;
  if (gid >= nvec) return;
  if constexpr (F32) {
    float* buf = (float*)bufV;
    const int c0 = (int)((gid * 4) & 63);
    f32x4 v = *(f32x4*)(buf + gid * 4);
#pragma unroll
    for (int i = 0; i < 4; ++i) {
      const float y = v[i] * fin[c0 + i] + fin[64 + c0 + i];
      v[i] = (y >= 0.f) ? y : SLOPE * y;
    }
    *(f32x4*)(buf + gid * 4) = v;
  } else {
    ushort_t* buf = (ushort_t*)bufV;
    const int c0 = (int)((gid * 8) & 63);
    short8 v = *(short8*)(buf + gid * 8);
#pragma unroll
    for (int i = 0; i < 8; ++i) {
      float y = bf2f((ushort_t)v[i]) * fin[c0 + i] + fin[64 + c0 + i];
      y = (y >= 0.f) ? y : SLOPE * y;
      v[i] = (short)f2bf(y);
    }
    *(short8*)(buf + gid * 8) = v;
  }
}

// ---------------------------------------------------------------------------
extern "C" void kernel_launch(void* const* d_in, const int* in_sizes, int n_in,
                              void* d_out, int out_size, void* d_ws, size_t ws_size,
                              hipStream_t stream)
{
  const float* x1   = (const float*)d_in[0];
  const float* x2   = (const float*)d_in[1];
  const int*   neigh= (const int*)d_in[2];
  const int*   top  = (const int*)d_in[3];
  const int*   down = (const int*)d_in[4];
  const float* upW  = (const float*)d_in[5];
  const float* upb  = (const float*)d_in[6];
  const float* c1W  = (const float*)d_in[7];
  const float* c1b  = (const float*)d_in[8];
  const float* g1   = (const float*)d_in[9];
  const float* b1   = (const float*)d_in[10];
  const float* c2W  = (const float*)d_in[11];
  const float* c2b  = (const float*)d_in[12];
  const float* g2   = (const float*)d_in[13];
  const float* b2   = (const float*)d_in[14];

  // d_out (83,887,104 B) staging plan — byte-audited, disjoint:
  //   [0,        41943552)  xup bf16 (B*NH,64)           = 41,943,552 B
  //   [41943552, 52429824)  x1bf bf16 (NR,128) per-batch = 10,486,272 B
  //   [52429824, 52544512)  upWt bf16 [448][128]         =    114,688 B
  //   [52544512, 52659200)  c1Wt bf16 [64][896]          =    114,688 B
  //   [52659200, 52692480)  st1 partials+final fp32      =     33,280 B
  // st1 is disjoint from xup/c1Wt (conv1's reads) -> no read/write race.
  // All regions dead before conv2 writes d_out.
  // ws: [0, 41943552) h bf16 (phase1) then y1 bf16. Gated tail (+90,624 B):
  //   c2Wt bf16 [64][448] (57,344 B) + st2 partials+final (33,280 B).
  char* dob = (char*)d_out;
  ushort_t* xupb = (ushort_t*)dob;
  ushort_t* x1bf = (ushort_t*)(dob + 41943552);
  ushort_t* upWt = (ushort_t*)(dob + 52429824);
  ushort_t* c1Wt = (ushort_t*)(dob + 52544512);
  float*    st1  = (float*)(dob + 52659200);
  float*    outb = (float*)d_out;

  ushort_t* hbuf = (ushort_t*)d_ws;
  ushort_t* ybuf = (ushort_t*)d_ws;

  const bool gated = ws_size >= (size_t)(41943552 + 90624);
  ushort_t* c2Wt = gated ? (ushort_t*)((char*)d_ws + 41943552) : nullptr;
  float*    st2  = gated ? (float*)((char*)d_ws + 41943552 + 57344)
                         : (float*)d_ws;   // fallback: overlays dead y1

  // Prep: weights (transposed bf16), zero st1 partials
  cvt_w_kernel<<<560, 256, 0, stream>>>(upW, c1W, c2W, upWt, c1Wt, c2Wt);
  zero_kernel<<<32, 256, 0, stream>>>(st1, 8192);

  // Phase 1 — per batch: x1->bf16; h = x1bf @ upWt + upb; xup = upconv(h)
  for (int b = 0; b < 2; ++b) {
    cvt_bf_kernel<<<2561, 256, 0, stream>>>(x1 + (size_t)b * M_UP * K_UP,
                                            x1bf, 655392LL);
    gemm_mfma<0, true, false><<<dim3(7, 321), 256, 0, stream>>>(
        x1bf, nullptr, nullptr, upWt, nullptr, upb, hbuf, nullptr,
        M_UP, N_UP, K_UP);
    build_xup_kernel<<<5121, 256, 0, stream>>>(
        hbuf, top, down, xupb + (size_t)b * NH * 64, (long long)NH * 8);
  }

  // Phase 2 — y1 = meshconv1([xup bf16 | x2 fp32]) -> ws; fused BN1 stats
  gemm_mfma<1, true, true><<<dim3(1, 2561), 256, 0, stream>>>(
      xupb, x2, neigh, c1Wt, nullptr, c1b, ybuf, st1, M_CV, 64, K_C1);
  finalize_kernel<<<1, 64, 0, stream>>>(st1, g1, b1);
  bnl_kernel<false><<<10241, 256, 0, stream>>>(ybuf, st1 + 8192,
                                               (long long)M_CV * 64 / 8);

  // Phase 3 — out = meshconv2(y1) -> d_out fp32 (+ fused BN2 stats if gated)
  if (gated) {
    zero_kernel<<<32, 256, 0, stream>>>(st2, 8192);
    gemm_mfma<2, true, true><<<dim3(1, 2561), 256, 0, stream>>>(
        ybuf, nullptr, neigh, c2Wt, nullptr, c2b, outb, st2, M_CV, 64, K_C2);
  } else {
    gemm_mfma<2, false, false><<<dim3(1, 2561), 256, 0, stream>>>(
        ybuf, nullptr, neigh, nullptr, c2W, c2b, outb, nullptr, M_CV, 64, K_C2);
    zero_kernel<<<32, 256, 0, stream>>>(st2, 8192);   // y1 dead now
    stats_f32_kernel<<<2048, 256, 0, stream>>>(outb, st2, M_CV);
  }
  finalize_kernel<<<1, 64, 0, stream>>>(st2, g2, b2);
  bnl_kernel<true><<<20481, 256, 0, stream>>>(outb, st2 + 8192,
                                              (long long)M_CV * 64 / 4);
}